// Round 6
// baseline (11.741 us; speedup 1.0000x reference)
//
#include <hip/hip_runtime.h>
#include <hip/hip_bf16.h>

// Embedding gather: out[b,s,:] = table[idx[b,s], :]
// idx: [128,512] int32, table: [3882,128] f32, out: [128,512,128] f32
//
// 4 rows per thread: 4 independent idx loads -> 16 independent float4
// gathers -> 16 nontemporal stores. Deepest per-thread MLP variant;
// tests whether the remaining gap over the ~5.6us traffic floor is
// latency (this should help) or fixed launch/ramp overhead (no change).

typedef float f32x4 __attribute__((ext_vector_type(4)));

__global__ __launch_bounds__(256) void embed_gather_kernel(
    const int* __restrict__ idx,       // 65536 indices
    const f32x4* __restrict__ tab4,    // 3882 * 32 float4
    f32x4* __restrict__ out4)          // 65536 * 32 float4
{
    int t = blockIdx.x * 256 + threadIdx.x;   // 0 .. 131071
    int col = t & 7;                           // float4 slot 0..7
    int rb = (t >> 3) * 4;                     // four consecutive rows

    int e0 = __builtin_nontemporal_load(&idx[rb + 0]);
    int e1 = __builtin_nontemporal_load(&idx[rb + 1]);
    int e2 = __builtin_nontemporal_load(&idx[rb + 2]);
    int e3 = __builtin_nontemporal_load(&idx[rb + 3]);

    const f32x4* __restrict__ s0 = tab4 + (size_t)e0 * 32 + col;
    const f32x4* __restrict__ s1 = tab4 + (size_t)e1 * 32 + col;
    const f32x4* __restrict__ s2 = tab4 + (size_t)e2 * 32 + col;
    const f32x4* __restrict__ s3 = tab4 + (size_t)e3 * 32 + col;
    f32x4* __restrict__ d0 = out4 + (size_t)(rb + 0) * 32 + col;
    f32x4* __restrict__ d1 = out4 + (size_t)(rb + 1) * 32 + col;
    f32x4* __restrict__ d2 = out4 + (size_t)(rb + 2) * 32 + col;
    f32x4* __restrict__ d3 = out4 + (size_t)(rb + 3) * 32 + col;

    // 16 independent gathers in flight
    f32x4 a0 = s0[0], b0 = s0[8], c0 = s0[16], q0 = s0[24];
    f32x4 a1 = s1[0], b1 = s1[8], c1 = s1[16], q1 = s1[24];
    f32x4 a2 = s2[0], b2 = s2[8], c2 = s2[16], q2 = s2[24];
    f32x4 a3 = s3[0], b3 = s3[8], c3 = s3[16], q3 = s3[24];

    __builtin_nontemporal_store(a0, &d0[0]);
    __builtin_nontemporal_store(b0, &d0[8]);
    __builtin_nontemporal_store(c0, &d0[16]);
    __builtin_nontemporal_store(q0, &d0[24]);
    __builtin_nontemporal_store(a1, &d1[0]);
    __builtin_nontemporal_store(b1, &d1[8]);
    __builtin_nontemporal_store(c1, &d1[16]);
    __builtin_nontemporal_store(q1, &d1[24]);
    __builtin_nontemporal_store(a2, &d2[0]);
    __builtin_nontemporal_store(b2, &d2[8]);
    __builtin_nontemporal_store(c2, &d2[16]);
    __builtin_nontemporal_store(q2, &d2[24]);
    __builtin_nontemporal_store(a3, &d3[0]);
    __builtin_nontemporal_store(b3, &d3[8]);
    __builtin_nontemporal_store(c3, &d3[16]);
    __builtin_nontemporal_store(q3, &d3[24]);
}

extern "C" void kernel_launch(void* const* d_in, const int* in_sizes, int n_in,
                              void* d_out, int out_size, void* d_ws, size_t ws_size,
                              hipStream_t stream) {
    const int* idx = (const int*)d_in[0];
    const f32x4* tab4 = (const f32x4*)d_in[1];
    f32x4* out4 = (f32x4*)d_out;

    // 65536 rows / 4 rows-per-thread * 8 threads-per-row = 131072 threads
    embed_gather_kernel<<<512, 256, 0, stream>>>(idx, tab4, out4);
}